// Round 3
// baseline (2103.622 us; speedup 1.0000x reference)
//
#include <hip/hip_runtime.h>

#define NPTS 8192
#define SPTS 2048
#define KS 32
#define CF 64
#define BQ 4
#define FPS_T 256
#define PPT 32               // points per thread
#define NPAIR 16             // vf2 pairs per thread
#define FPS_SHIFT 8          // log2(FPS_T)

#define OFF_GROUPED 24576                    // B*S*3
#define GROUPED_SZ  17563648                 // B*67*S*K
#define OFF_FPSIDX  (OFF_GROUPED + GROUPED_SZ)

typedef __attribute__((ext_vector_type(2))) float vf2;
typedef unsigned long long u64;

// Forced packed-f32 VALU ops (VOP3P, CDNA2+). Guarantees 1 instr per 2 lanes-ops.
static __device__ __forceinline__ vf2 pk_add(vf2 a, vf2 b) {
    vf2 d; asm("v_pk_add_f32 %0, %1, %2" : "=v"(d) : "v"(a), "v"(b)); return d;
}
static __device__ __forceinline__ vf2 pk_mul(vf2 a, vf2 b) {
    vf2 d; asm("v_pk_mul_f32 %0, %1, %2" : "=v"(d) : "v"(a), "v"(b)); return d;
}

// Two-phase DPP wave-64 max (round-1-proven fastest form).
// bound_ctrl=true -> OOB lanes read 0; harmless for max of nonneg values.
#define DPPMAXF(x, ctrl) do {                                                   \
    int _t = __builtin_amdgcn_mov_dpp(__float_as_int(x), (ctrl), 0xf, 0xf, true); \
    x = fmaxf((x), __int_as_float(_t));                                         \
} while (0)

#define DPPMAXU(x, ctrl) do {                                                   \
    unsigned _u = (unsigned)__builtin_amdgcn_mov_dpp((int)(x), (ctrl), 0xf, 0xf, true); \
    x = ((x) > _u) ? (x) : _u;                                                  \
} while (0)

// ---------------- FPS: one block per batch, 1 wave per SIMD ----------------
// Issue-bound kernel: minimize per-SIMD instruction count. 4 waves, 32 pts/thread.
// Loop body has ZERO global-memory ops.
__global__ __launch_bounds__(FPS_T)
void fps_kernel(const float* __restrict__ xyz, float* __restrict__ out)
{
#pragma clang fp contract(off)
    __shared__ float sx[NPTS], sy[NPTS], sz[NPTS];   // 96 KiB coord planes
    __shared__ float4 rres[SPTS];                     // 32 KiB per-iter results
    __shared__ __align__(16) u64 slots[2][4];         // parity double-buffer
    const int b    = blockIdx.x;
    const int tid  = threadIdx.x;
    const int wv   = tid >> 6;
    const int lane = tid & 63;
    const float* xb = xyz + (size_t)b * (NPTS * 3);

    // Strided ownership: offset o in [0,32) -> point tid + 256*o.
    // Pair j: component x = o=2j, y = o=2j+1.
    vf2 PX[NPAIR], PY[NPAIR], PZ[NPAIR], MD[NPAIR];
#pragma unroll
    for (int j = 0; j < NPAIR; ++j) {
        const int p0 = tid + 512 * j;
        const int p1 = p0 + 256;
        const float x0 = xb[p0 * 3 + 0], y0 = xb[p0 * 3 + 1], z0 = xb[p0 * 3 + 2];
        const float x1 = xb[p1 * 3 + 0], y1 = xb[p1 * 3 + 1], z1 = xb[p1 * 3 + 2];
        sx[p0] = x0; sy[p0] = y0; sz[p0] = z0;
        sx[p1] = x1; sy[p1] = y1; sz[p1] = z1;
        vf2 vx; vx.x = x0; vx.y = x1; PX[j] = vx;
        vf2 vy; vy.x = y0; vy.y = y1; PY[j] = vy;
        vf2 vz; vz.x = z0; vz.y = z1; PZ[j] = vz;
        vf2 vm; vm.x = 1e10f; vm.y = 1e10f; MD[j] = vm;
    }

    // iteration 0: center = point 0; result buffered in LDS, written at end
    float qx = xb[0], qy = xb[1], qz = xb[2];
    if (tid == 0) {
        float4 r; r.x = qx; r.y = qy; r.z = qz; r.w = 0.0f;
        rres[0] = r;
    }

    for (int i = 1; i < SPTS; ++i) {
        // negate q once: a - b == a + (-b) exactly (IEEE), keeps numpy order
        const float nqx = -qx, nqy = -qy, nqz = -qz;
        vf2 vnx; vnx.x = nqx; vnx.y = nqx;
        vf2 vny; vny.x = nqy; vny.y = nqy;
        vf2 vnz; vnz.x = nqz; vnz.y = nqz;

        // min-dist update: exact numpy rounding order (dx*dx+dy*dy)+dz*dz, no fma
#pragma unroll
        for (int j = 0; j < NPAIR; ++j) {
            const vf2 dx = pk_add(PX[j], vnx);
            const vf2 dy = pk_add(PY[j], vny);
            const vf2 dz = pk_add(PZ[j], vnz);
            const vf2 xx = pk_mul(dx, dx);
            const vf2 yy = pk_mul(dy, dy);
            const vf2 zz = pk_mul(dz, dz);
            const vf2 s  = pk_add(pk_add(xx, yy), zz);
            MD[j] = __builtin_elementwise_min(MD[j], s);
        }

        // pairwise max tree over 16 vf2, then horizontal
        vf2 t0 = __builtin_elementwise_max(MD[0],  MD[1]);
        vf2 t1 = __builtin_elementwise_max(MD[2],  MD[3]);
        vf2 t2 = __builtin_elementwise_max(MD[4],  MD[5]);
        vf2 t3 = __builtin_elementwise_max(MD[6],  MD[7]);
        vf2 t4 = __builtin_elementwise_max(MD[8],  MD[9]);
        vf2 t5 = __builtin_elementwise_max(MD[10], MD[11]);
        vf2 t6 = __builtin_elementwise_max(MD[12], MD[13]);
        vf2 t7 = __builtin_elementwise_max(MD[14], MD[15]);
        t0 = __builtin_elementwise_max(t0, t1);
        t2 = __builtin_elementwise_max(t2, t3);
        t4 = __builtin_elementwise_max(t4, t5);
        t6 = __builtin_elementwise_max(t6, t7);
        t0 = __builtin_elementwise_max(t0, t2);
        t4 = __builtin_elementwise_max(t4, t6);
        t0 = __builtin_elementwise_max(t0, t4);
        const float best = fmaxf(t0.x, t0.y);

        // phase 1: wave max of dist via DPP, accumulates into lane 63
        float wm = best;
        DPPMAXF(wm, 0x111);  // row_shr:1
        DPPMAXF(wm, 0x112);  // row_shr:2
        DPPMAXF(wm, 0x114);  // row_shr:4
        DPPMAXF(wm, 0x118);  // row_shr:8
        DPPMAXF(wm, 0x142);  // row_bcast:15
        DPPMAXF(wm, 0x143);  // row_bcast:31
        const float wavemax =
            __int_as_float(__builtin_amdgcn_readlane(__float_as_int(wm), 63));

        // smallest owned offset o with md[o]==best: eq-bitmask + ctz
        unsigned m = 0u;
#pragma unroll
        for (int j = 0; j < NPAIR; ++j) {
            m |= (MD[j].x == best) ? (1u << (2 * j))     : 0u;
            m |= (MD[j].y == best) ? (1u << (2 * j + 1)) : 0u;
        }
        const int bo = __builtin_ctz(m);
        const int bidx = tid + (bo << FPS_SHIFT);

        // phase 2: among exact ties, max of (8191-idx) == smallest idx
        unsigned cand = (best == wavemax) ? (unsigned)(NPTS - 1 - bidx) : 0u;
        DPPMAXU(cand, 0x111);
        DPPMAXU(cand, 0x112);
        DPPMAXU(cand, 0x114);
        DPPMAXU(cand, 0x118);
        DPPMAXU(cand, 0x142);
        DPPMAXU(cand, 0x143);

        // lane 63 holds both wavemax and candmax: pack + write, no 2nd readlane
        if (lane == 63)
            slots[i & 1][wv] = ((u64)__float_as_uint(wm) << 32) | cand;
        __syncthreads();                      // the only barrier; no vmem to drain

        // cross-wave reduce: 2 x 16B broadcast LDS reads + 3-node u64 tree
        const ulonglong2* sp = (const ulonglong2*)slots[i & 1];
        const ulonglong2 pA = sp[0], pB = sp[1];
        u64 a = pA.x > pA.y ? pA.x : pA.y;
        u64 c = pB.x > pB.y ? pB.x : pB.y;
        const u64 g = a > c ? a : c;
        const int widx = (NPTS - 1) - (int)(unsigned)g;

        // winner coords from LDS planes (uniform addr -> broadcast)
        qx = sx[widx]; qy = sy[widx]; qz = sz[widx];

        if (tid == 0) {
            float4 r; r.x = qx; r.y = qy; r.z = qz; r.w = (float)widx;
            rres[i] = r;                      // ds_write_b128, off critical path
        }
    }

    // bulk writeback of all per-iteration results (one time)
    __syncthreads();
    float* newxyz = out;
    float* fpsidx = out + OFF_FPSIDX;
#pragma unroll
    for (int j = 0; j < 8; ++j) {
        const int i = tid + (j << FPS_SHIFT);
        const float4 r = rres[i];
        fpsidx[(size_t)b * SPTS + i] = r.w;
        const size_t o = ((size_t)b * SPTS + i) * 3;
        newxyz[o + 0] = r.x; newxyz[o + 1] = r.y; newxyz[o + 2] = r.z;
    }
}

// ---------------- ball query + grouping: one wave per center ----------------
__global__ __launch_bounds__(256)
void ballgroup_kernel(const float* __restrict__ xyz, const float* __restrict__ feat,
                      float* out)
{
#pragma clang fp contract(off)
    __shared__ int idxl[4][KS];
    const int tid    = threadIdx.x;
    const int wv     = tid >> 6;
    const int lane   = tid & 63;
    const int center = blockIdx.x * 4 + wv;
    const int b      = center >> 11;          // / SPTS
    const int s      = center & (SPTS - 1);
    const float* xb  = xyz + (size_t)b * (NPTS * 3);
    const float* newxyz = out;                // written by fps_kernel earlier in stream
    const float cx = newxyz[(size_t)center * 3 + 0];
    const float cy = newxyz[(size_t)center * 3 + 1];
    const float cz = newxyz[(size_t)center * 3 + 2];

    if (lane == 0) idxl[wv][0] = 0;           // default when zero hits

    int cnt = 0;
    for (int nb = 0; nb < NPTS; nb += 64) {
        const int p = nb + lane;
        const float x = xb[p * 3 + 0];
        const float y = xb[p * 3 + 1];
        const float z = xb[p * 3 + 2];
        const float dx = cx - x, dy = cy - y, dz = cz - z;
        const float d2 = (dx * dx + dy * dy) + dz * dz;
        // f32 'd2 <= 0.04f' == numpy 'f32 d2 < float64(0.2*0.2)'
        const bool in = (d2 <= 0.04f);
        const unsigned long long mk = __ballot(in);
        if (in) {
            const int pos = cnt + __popcll(mk & ((1ull << lane) - 1ull));
            if (pos < KS) idxl[wv][pos] = p;
        }
        cnt += (int)__popcll(mk);
        if (cnt >= KS) break;                 // cnt is wave-uniform
    }
    const int cc = cnt < KS ? cnt : KS;

    // pad short lists with first hit (or 0), write padded list back
    int myidx = 0;
    if (lane < KS) {
        myidx = (lane < cc) ? idxl[wv][lane] : idxl[wv][0];
        idxl[wv][lane] = myidx;
    }

    float* grouped = out + OFF_GROUPED;
    const size_t chstride = (size_t)SPTS * KS;                    // 65536
    const size_t base67   = (size_t)b * 67 * chstride + (size_t)s * KS;

    // channels 0..2: recentered coords (point - center)
    if (lane < KS) {
        const float gx = xb[(size_t)myidx * 3 + 0] - cx;
        const float gy = xb[(size_t)myidx * 3 + 1] - cy;
        const float gz = xb[(size_t)myidx * 3 + 2] - cz;
        grouped[base67 + 0 * chstride + lane] = gx;
        grouped[base67 + 1 * chstride + lane] = gy;
        grouped[base67 + 2 * chstride + lane] = gz;
    }

    // channels 3..66: feature gather; lanes = (k, c-half)
    const int k    = lane & (KS - 1);
    const int half = lane >> 5;
    const int gi   = idxl[wv][k];
    const float* fb = feat + (size_t)b * CF * NPTS;
    const size_t obase = base67 + 3 * chstride + (size_t)k;
#pragma unroll 8
    for (int c0 = 0; c0 < 32; ++c0) {
        const int c = c0 * 2 + half;
        grouped[obase + (size_t)c * chstride] = fb[(size_t)c * NPTS + gi];
    }
}

extern "C" void kernel_launch(void* const* d_in, const int* in_sizes, int n_in,
                              void* d_out, int out_size, void* d_ws, size_t ws_size,
                              hipStream_t stream) {
    const float* xyz  = (const float*)d_in[0];
    const float* feat = (const float*)d_in[1];
    float* out = (float*)d_out;
    fps_kernel<<<dim3(BQ), dim3(FPS_T), 0, stream>>>(xyz, out);
    ballgroup_kernel<<<dim3((BQ * SPTS) / 4), dim3(256), 0, stream>>>(xyz, feat, out);
}